// Round 5
// baseline (512.593 us; speedup 1.0000x reference)
//
#include <hip/hip_runtime.h>

// NestLinearQuantizer: out = quant(x) @ dequant(packed)^T + bias
// Factored to int8 GEMM:  out[t,o] = as*scale[o]*(dot_i8[t,o] - zp[o]*rowsum[t]) + bias[o]
// where q[o,i] = max(hi_nibble*16 + (packed_low - 144), -128)  (exact int8),
// xi8 = clip(rint(x/as), -128, 127).

typedef int v4i __attribute__((ext_vector_type(4)));
typedef int v2i __attribute__((ext_vector_type(2)));

#define TOKENS 256
#define INF 8192
#define OUTF 8192
#define BN 16
#define KSTEP 128
#define NITER 64  // INF / KSTEP

// ---------------- Kernel 1: quantize activations to int8 + per-token rowsum --------
__global__ __launch_bounds__(256) void quant_x_kernel(
    const float* __restrict__ x, const float* __restrict__ act_scale,
    signed char* __restrict__ xi8, int* __restrict__ rowsum)
{
    const int t = blockIdx.x;
    const int j = threadIdx.x;
    const float s = act_scale[0];
    const float4* xrow = (const float4*)(x + (size_t)t * INF);
    int* qrow = (int*)(xi8 + (size_t)t * INF);
    int lsum = 0;
#pragma unroll
    for (int c = 0; c < 8; ++c) {
        float4 v = xrow[j + c * 256];
        int q0 = (int)rintf(v.x / s); q0 = q0 < -128 ? -128 : (q0 > 127 ? 127 : q0);
        int q1 = (int)rintf(v.y / s); q1 = q1 < -128 ? -128 : (q1 > 127 ? 127 : q1);
        int q2 = (int)rintf(v.z / s); q2 = q2 < -128 ? -128 : (q2 > 127 ? 127 : q2);
        int q3 = (int)rintf(v.w / s); q3 = q3 < -128 ? -128 : (q3 > 127 ? 127 : q3);
        qrow[j + c * 256] = (q0 & 255) | ((q1 & 255) << 8) | ((q2 & 255) << 16) | ((q3 & 255) << 24);
        lsum += q0 + q1 + q2 + q3;
    }
#pragma unroll
    for (int off = 32; off > 0; off >>= 1) lsum += __shfl_down(lsum, off, 64);
    __shared__ int wsum[4];
    if ((j & 63) == 0) wsum[j >> 6] = lsum;
    __syncthreads();
    if (j == 0) rowsum[t] = wsum[0] + wsum[1] + wsum[2] + wsum[3];
}

// ---------------- Kernel 2: fused unpack + int8 MFMA GEMM + epilogue ----------------
// BM=256 (all tokens) x BN=16 -> 512 blocks (2/CU). K-step 128, 64 iterations.
// 256 thr = 4 waves; wave w owns rows [w*64, w*64+64) x 16 cols = 4 tiles of 16x16x64
// per k-half. B unpacked once into LDS (shared by 4 waves); A global->VGPR (L2-hot).
// Depth-2 register prefetch with compile-time slots; lgkm-only barriers so global
// loads stay in flight across barriers.
__device__ __forceinline__ int unpack4(v4i pl, v2i ph) {
    // q = max(hi_nibble*16 + pl - 144, -128), packed 4x i8
    int q0 = (ph[0] & 0xF0)        + pl[0] - 144; q0 = q0 < -128 ? -128 : q0;
    int q1 = ((ph[0] & 0x0F) << 4) + pl[1] - 144; q1 = q1 < -128 ? -128 : q1;
    int q2 = (ph[1] & 0xF0)        + pl[2] - 144; q2 = q2 < -128 ? -128 : q2;
    int q3 = ((ph[1] & 0x0F) << 4) + pl[3] - 144; q3 = q3 < -128 ? -128 : q3;
    return (q0 & 255) | ((q1 & 255) << 8) | ((q2 & 255) << 16) | ((q3 & 255) << 24);
}

__global__ __launch_bounds__(256, 2) void gemm_kernel(
    const signed char* __restrict__ xi8, const int* __restrict__ rowsum,
    const int* __restrict__ packed_high, const int* __restrict__ packed_low,
    const float* __restrict__ scale, const float* __restrict__ zero_point,
    const float* __restrict__ bias, const float* __restrict__ act_scale,
    float* __restrict__ out)
{
    // 8 kg-slabs per buffer, slab = 16 cols * 16 B + 32 B pad = 288 B
    // (slab stride 72 words = 8 mod 32 banks -> staging writes 2-way = free)
    __shared__ __align__(16) char Blds[2 * 2304];

    const int tid  = threadIdx.x;
    const int lane = tid & 63;
    const int w    = tid >> 6;
    const int n0   = blockIdx.x * BN;

    // --- B staging: thread -> (col so, 4 k at si) in each 64-k half ---
    const int so = tid >> 4;          // 0..15
    const int si = (tid & 15) << 2;   // 0..60
    const int* pl_ptr = packed_low  + (size_t)(n0 + so) * INF       + si;
    const int* ph_ptr = packed_high + (size_t)(n0 + so) * (INF / 2) + (si >> 1);
    const int wof0 = (si >> 4) * 288 + so * 16 + (si & 12);
    const int wof1 = wof0 + 4 * 288;

    // --- B fragment read offsets (kg = kt*4 + lane>>4, col = lane&15) ---
    const int rof0 = (lane >> 4) * 288 + (lane & 15) * 16;
    const int rof1 = rof0 + 4 * 288;

    // --- A: lane holds row w*64 + f*16 + (lane&15), k-slice (lane>>4)*16 ---
    const signed char* aptr = xi8 + (size_t)((w << 6) + (lane & 15)) * INF + ((lane >> 4) << 4);

    v4i acc0 = {0,0,0,0}, acc1 = {0,0,0,0}, acc2 = {0,0,0,0}, acc3 = {0,0,0,0};

    v4i plA0, plA1, plB0, plB1;
    v2i phA0, phA1, phB0, phB1;
    v4i aA[8], aB[8];

#define LOAD_B(PL0, PL1, PH0, PH1, T) {                                         \
        const int k0_ = (T) * KSTEP;                                            \
        PL0 = __builtin_nontemporal_load((const v4i*)(pl_ptr + k0_));           \
        PL1 = __builtin_nontemporal_load((const v4i*)(pl_ptr + k0_ + 64));      \
        PH0 = __builtin_nontemporal_load((const v2i*)(ph_ptr + (k0_ >> 1)));    \
        PH1 = __builtin_nontemporal_load((const v2i*)(ph_ptr + (k0_ >> 1) + 32)); }

#define LOAD_A(AR, T) {                                                         \
        const int k0_ = (T) * KSTEP;                                            \
        _Pragma("unroll")                                                       \
        for (int f = 0; f < 4; ++f) {                                           \
            AR[f]     = *(const v4i*)(aptr + f * 16 * INF + k0_);               \
            AR[f + 4] = *(const v4i*)(aptr + f * 16 * INF + k0_ + 64);          \
        } }

#define BODY(PL0, PL1, PH0, PH1, AR, T, BUF) {                                  \
        *(int*)(Blds + (BUF) * 2304 + wof0) = unpack4(PL0, PH0);                \
        *(int*)(Blds + (BUF) * 2304 + wof1) = unpack4(PL1, PH1);                \
        { const int tn_ = ((T) + 2 < NITER) ? (T) + 2 : NITER - 1;              \
          LOAD_B(PL0, PL1, PH0, PH1, tn_); }                                    \
        /* drain our ds_write (tile T) AND our ds_reads (tile T-2) only; */     \
        /* vmcnt NOT drained -> prefetch stays in flight across barrier. */     \
        asm volatile("s_waitcnt lgkmcnt(0)" ::: "memory");                      \
        __builtin_amdgcn_s_barrier();                                           \
        v4i b0_ = *(const v4i*)(Blds + (BUF) * 2304 + rof0);                    \
        v4i b1_ = *(const v4i*)(Blds + (BUF) * 2304 + rof1);                    \
        acc0 = __builtin_amdgcn_mfma_i32_16x16x64_i8(AR[0], b0_, acc0, 0, 0, 0);\
        acc1 = __builtin_amdgcn_mfma_i32_16x16x64_i8(AR[1], b0_, acc1, 0, 0, 0);\
        acc2 = __builtin_amdgcn_mfma_i32_16x16x64_i8(AR[2], b0_, acc2, 0, 0, 0);\
        acc3 = __builtin_amdgcn_mfma_i32_16x16x64_i8(AR[3], b0_, acc3, 0, 0, 0);\
        acc0 = __builtin_amdgcn_mfma_i32_16x16x64_i8(AR[4], b1_, acc0, 0, 0, 0);\
        acc1 = __builtin_amdgcn_mfma_i32_16x16x64_i8(AR[5], b1_, acc1, 0, 0, 0);\
        acc2 = __builtin_amdgcn_mfma_i32_16x16x64_i8(AR[6], b1_, acc2, 0, 0, 0);\
        acc3 = __builtin_amdgcn_mfma_i32_16x16x64_i8(AR[7], b1_, acc3, 0, 0, 0);\
        { const int tn_ = ((T) + 2 < NITER) ? (T) + 2 : NITER - 1;              \
          LOAD_A(AR, tn_); } }

    LOAD_B(plA0, plA1, phA0, phA1, 0); LOAD_A(aA, 0);
    LOAD_B(plB0, plB1, phB0, phB1, 1); LOAD_A(aB, 1);

    for (int t = 0; t < NITER; t += 2) {
        BODY(plA0, plA1, phA0, phA1, aA, t,     0);
        BODY(plB0, plB1, phB0, phB1, aB, t + 1, 1);
    }
#undef BODY
#undef LOAD_A
#undef LOAD_B

    // --- epilogue: D layout col=lane&15, row=(lane>>4)*4+reg ---
    const float as = act_scale[0];
    const int col  = lane & 15;
    const int o    = n0 + col;
    const float sc = as * scale[o];
    const float zo = zero_point[o];
    const float bo = bias[o];
    const int rbase = (w << 6) + ((lane >> 4) << 2);

#define EPI(ACC, F) { _Pragma("unroll")                                        \
    for (int r = 0; r < 4; ++r) {                                              \
        const int trow = rbase + (F) * 16 + r;                                 \
        const float fv = (float)ACC[r] - zo * (float)rowsum[trow];             \
        out[(size_t)trow * OUTF + o] = fmaf(sc, fv, bo);                       \
    } }
    EPI(acc0, 0) EPI(acc1, 1) EPI(acc2, 2) EPI(acc3, 3)
#undef EPI
}

extern "C" void kernel_launch(void* const* d_in, const int* in_sizes, int n_in,
                              void* d_out, int out_size, void* d_ws, size_t ws_size,
                              hipStream_t stream)
{
    const float* x           = (const float*)d_in[0];
    const int*   packed_high = (const int*)d_in[1];
    const int*   packed_low  = (const int*)d_in[2];
    const float* scale       = (const float*)d_in[3];
    const float* zero_point  = (const float*)d_in[4];
    const float* bias        = (const float*)d_in[5];
    const float* act_scale   = (const float*)d_in[6];
    float* out = (float*)d_out;

    signed char* xi8 = (signed char*)d_ws;
    int* rowsum = (int*)((char*)d_ws + (size_t)TOKENS * INF);

    quant_x_kernel<<<TOKENS, 256, 0, stream>>>(x, act_scale, xi8, rowsum);
    gemm_kernel<<<OUTF / BN, 256, 0, stream>>>(xi8, rowsum, packed_high, packed_low,
                                               scale, zero_point, bias, act_scale, out);
}

// Round 6
// 492.841 us; speedup vs baseline: 1.0401x; 1.0401x over previous
//
#include <hip/hip_runtime.h>

// NestLinearQuantizer: out = quant(x) @ dequant(packed)^T + bias
// Exact int8 factorization: out[t,o] = as*scale[o]*(dot_i8[t,o] - zp[o]*rowsum[t]) + bias[o]
//   q[o,i] = max(hi_nibble*16 + (packed_low - 144), -128)   (exact int8)
//   xi8    = clip(rint(x/as), -128, 127)
//
// GEMM decomposition: wave = M=256 x N=16 output tile over a 2048-k quarter.
// Block = 4 waves k-splitting the same N-tile (k-quarters), joined only by a
// one-time LDS integer reduce. NO barriers / NO LDS / NO inline asm in the
// main loop. A is pre-packed by the quant kernel into MFMA-fragment order so
// every A load is a 1KB-contiguous wave access (8 fully-used lines/instr).

typedef int v4i __attribute__((ext_vector_type(4)));

#define TOKENS 256
#define INF 8192
#define OUTF 8192
#define NSTEP 32   // k-steps of 64 per wave (k-quarter = 2048)

// ---------------- Kernel 1: quantize x -> int8 in fragment layout + rowsum ---------
// Apk word index: kb*4096 + f*256 + lane*4 + w4  <=>
//   xi8[row = f*16 + (lane&15)][k = kb*64 + (lane>>4)*16 + w4*4 + byte]
__global__ __launch_bounds__(256) void quant_x_kernel(
    const float* __restrict__ x, const float* __restrict__ act_scale,
    int* __restrict__ apk, int* __restrict__ rowsum)
{
    const int t = blockIdx.x;    // token row
    const int j = threadIdx.x;
    const float s = act_scale[0];
    const float4* xrow = (const float4*)(x + (size_t)t * INF);
    const int f    = t >> 4;
    const int llow = t & 15;
    int lsum = 0;
#pragma unroll
    for (int c = 0; c < 8; ++c) {
        const int kw = j + c * 256;          // k-word 0..2047
        float4 v = xrow[kw];
        // jnp.round == round-half-to-even == rintf
        int q0 = (int)rintf(v.x / s); q0 = q0 < -128 ? -128 : (q0 > 127 ? 127 : q0);
        int q1 = (int)rintf(v.y / s); q1 = q1 < -128 ? -128 : (q1 > 127 ? 127 : q1);
        int q2 = (int)rintf(v.z / s); q2 = q2 < -128 ? -128 : (q2 > 127 ? 127 : q2);
        int q3 = (int)rintf(v.w / s); q3 = q3 < -128 ? -128 : (q3 > 127 ? 127 : q3);
        const int word = (q0 & 255) | ((q1 & 255) << 8) | ((q2 & 255) << 16) | ((q3 & 255) << 24);
        const int k0 = kw << 2;
        const int kb = k0 >> 6;
        const int ks = k0 & 63;
        const int lane = ((ks >> 4) << 4) + llow;
        apk[kb * 4096 + f * 256 + (lane << 2) + ((ks & 15) >> 2)] = word;
        lsum += q0 + q1 + q2 + q3;
    }
#pragma unroll
    for (int off = 32; off > 0; off >>= 1) lsum += __shfl_down(lsum, off, 64);
    __shared__ int wsum[4];
    if ((j & 63) == 0) wsum[j >> 6] = lsum;
    __syncthreads();
    if (j == 0) rowsum[t] = wsum[0] + wsum[1] + wsum[2] + wsum[3];
}

// ---------------- Kernel 2: barrier-free fused unpack + int8 MFMA GEMM -------------
__device__ __forceinline__ int unpack4(v4i pl, int pha, int phb) {
    // q = max(nib*16 + pl - 144, -128); pha covers k{0,1}, phb k{2,3} (hi nib = even k)
    int q0 = (pha & 0xF0)        + pl[0] - 144; q0 = q0 < -128 ? -128 : q0;
    int q1 = ((pha & 0x0F) << 4) + pl[1] - 144; q1 = q1 < -128 ? -128 : q1;
    int q2 = (phb & 0xF0)        + pl[2] - 144; q2 = q2 < -128 ? -128 : q2;
    int q3 = ((phb & 0x0F) << 4) + pl[3] - 144; q3 = q3 < -128 ? -128 : q3;
    return (q0 & 255) | ((q1 & 255) << 8) | ((q2 & 255) << 16) | ((q3 & 255) << 24);
}

__global__ __launch_bounds__(256) void gemm_kernel(
    const int* __restrict__ apk, const int* __restrict__ rowsum,
    const int* __restrict__ packed_high, const int* __restrict__ packed_low,
    const float* __restrict__ scale, const float* __restrict__ zero_point,
    const float* __restrict__ bias, const float* __restrict__ act_scale,
    float* __restrict__ out)
{
    __shared__ int accbuf[16][4][64];   // [frag][reg][lane], 16 KB, reduce only

    const int tid  = threadIdx.x;
    const int lane = tid & 63;
    const int w    = tid >> 6;         // k-quarter
    const int n0   = blockIdx.x * 16;
    const int col  = lane & 15;
    const int kq16 = lane >> 4;

    // --- B pointers: lane owns col o, 16-k slice at kbase (advances 64/step) ---
    const int o     = n0 + col;
    const int kbase = w * (NSTEP * 64) + kq16 * 16;
    const int* pl = packed_low  + (size_t)o * INF       + kbase;
    const int* ph = packed_high + (size_t)o * (INF / 2) + (kbase >> 1);

    // --- A base: fragment-packed, this wave's k-quarter ---
    const int* ab = apk + w * NSTEP * 4096 + (lane << 2);

    v4i acc[16];
#pragma unroll
    for (int f = 0; f < 16; ++f) acc[f] = (v4i){0, 0, 0, 0};

    v4i a[16], plv[4], phv[2];
#pragma unroll
    for (int m = 0; m < 4; ++m) plv[m] = *(const v4i*)(pl + 4 * m);
#pragma unroll
    for (int m = 0; m < 2; ++m) phv[m] = *(const v4i*)(ph + 4 * m);
#pragma unroll
    for (int f = 0; f < 16; ++f) a[f] = *(const v4i*)(ab + f * 256);

    for (int t = 0; t < NSTEP; ++t) {
        const int tn = (t + 1) & (NSTEP - 1);   // wrap keeps addresses in-bounds
        // unpack B(t) from regs loaded last iteration
        v4i b;
        b[0] = unpack4(plv[0], phv[0][0], phv[0][1]);
        b[1] = unpack4(plv[1], phv[0][2], phv[0][3]);
        b[2] = unpack4(plv[2], phv[1][0], phv[1][1]);
        b[3] = unpack4(plv[3], phv[1][2], phv[1][3]);
        // issue B(t+1) (HBM stream; ~1 kstep of flight time)
#pragma unroll
        for (int m = 0; m < 4; ++m) plv[m] = *(const v4i*)(pl + tn * 64 + 4 * m);
#pragma unroll
        for (int m = 0; m < 2; ++m) phv[m] = *(const v4i*)(ph + tn * 32 + 4 * m);
        // MFMA; reload each A frag for t+1 right after its use (1KB-contiguous loads)
        const int* abn = ab + tn * 4096;
#pragma unroll
        for (int f = 0; f < 16; ++f) {
            acc[f] = __builtin_amdgcn_mfma_i32_16x16x64_i8(a[f], b, acc[f], 0, 0, 0);
            a[f] = *(const v4i*)(abn + f * 256);
        }
    }

    // --- one-time integer reduce across the 4 k-quarter waves ---
    int* flat = &accbuf[0][0][0];
#pragma unroll
    for (int i = 0; i < 4; ++i) *(v4i*)(flat + tid * 16 + i * 4) = (v4i){0, 0, 0, 0};
    __syncthreads();
#pragma unroll
    for (int f = 0; f < 16; ++f)
#pragma unroll
        for (int r = 0; r < 4; ++r)
            atomicAdd(&accbuf[f][r][lane], acc[f][r]);
    __syncthreads();

    // --- epilogue: wave w handles frags w*4..w*4+3 ---
    const float as = act_scale[0];
    const float sc = as * scale[o];
    const float zo = zero_point[o];
    const float bo = bias[o];
#pragma unroll
    for (int ff = 0; ff < 4; ++ff) {
        const int f = (w << 2) + ff;
        const int rbase = f * 16 + kq16 * 4;   // D: col = lane&15, row = (lane>>4)*4 + r
        v4i rs = *(const v4i*)(rowsum + rbase);
#pragma unroll
        for (int r = 0; r < 4; ++r) {
            const float fv = (float)accbuf[f][r][lane] - zo * (float)rs[r];
            out[(size_t)(rbase + r) * OUTF + o] = fmaf(sc, fv, bo);
        }
    }
}

extern "C" void kernel_launch(void* const* d_in, const int* in_sizes, int n_in,
                              void* d_out, int out_size, void* d_ws, size_t ws_size,
                              hipStream_t stream)
{
    const float* x           = (const float*)d_in[0];
    const int*   packed_high = (const int*)d_in[1];
    const int*   packed_low  = (const int*)d_in[2];
    const float* scale       = (const float*)d_in[3];
    const float* zero_point  = (const float*)d_in[4];
    const float* bias        = (const float*)d_in[5];
    const float* act_scale   = (const float*)d_in[6];
    float* out = (float*)d_out;

    int* apk    = (int*)d_ws;                                  // 2 MB fragment-packed xi8
    int* rowsum = (int*)((char*)d_ws + (size_t)TOKENS * INF);  // 1 KB

    quant_x_kernel<<<TOKENS, 256, 0, stream>>>(x, act_scale, apk, rowsum);
    gemm_kernel<<<OUTF / 16, 256, 0, stream>>>(apk, rowsum, packed_high, packed_low,
                                               scale, zero_point, bias, act_scale, out);
}